// Round 14
// baseline (137.965 us; speedup 1.0000x reference)
//
#include <hip/hip_runtime.h>
#include <hip/hip_bf16.h>

typedef __hip_bfloat16 bf16;
typedef __attribute__((ext_vector_type(8))) short bf16x8;   // 8 bf16 = 4 VGPRs (MFMA A/B frag)
typedef __attribute__((ext_vector_type(4))) float f32x4;    // MFMA C/D frag
typedef __attribute__((ext_vector_type(2))) unsigned int u32x2;
typedef __attribute__((ext_vector_type(4))) unsigned int u32x4;

#define MFMA(a, b, c) __builtin_amdgcn_mfma_f32_16x16x32_bf16((a), (b), (c), 0, 0, 0)

static __device__ __forceinline__ float bf2f(bf16 b) { return __bfloat162float(b); }

// Packed f32->bf16 (truncation) via single v_perm_b32 (passed r7..r13).
static __device__ __forceinline__ unsigned pk2(float a, float b) {
    return __builtin_amdgcn_perm(__builtin_bit_cast(unsigned, b),
                                 __builtin_bit_cast(unsigned, a), 0x07060302u);
}

// Quad-row swaps (rows = 16-lane groups). Verified in r13.
static __device__ __forceinline__ void sw32(unsigned& a, unsigned& b) {
    u32x2 r = __builtin_amdgcn_permlane32_swap(a, b, false, false);
    a = r[0]; b = r[1];
}
static __device__ __forceinline__ void sw16(unsigned& a, unsigned& b) {
    u32x2 r = __builtin_amdgcn_permlane16_swap(a, b, false, false);
    a = r[0]; b = r[1];
}

// Async global->LDS DMA, 16B per lane. LDS dest = wave-uniform base + lane*16.
static __device__ __forceinline__ void gload16(const void* g, void* l) {
    __builtin_amdgcn_global_load_lds(
        (const __attribute__((address_space(1))) void*)g,
        (__attribute__((address_space(3))) void*)l, 16, 0, 0);
}

static __device__ __forceinline__ float quad_max(float x) {
    x = fmaxf(x, __shfl_xor(x, 16));
    x = fmaxf(x, __shfl_xor(x, 32));
    return x;
}
static __device__ __forceinline__ float quad_sum(float x) {
    x += __shfl_xor(x, 16);
    x += __shfl_xor(x, 32);
    return x;
}

// ---------------------------------------------------------------------------
// Phase 0 (merged): blocks [0,4352): convert X + dist_emb to bf16;
// blocks [4352,5120): transpose Wq/Wk/Wv f32 [in][out] -> WT bf16 [out][in].
// ---------------------------------------------------------------------------
__global__ void prep_all(const float* __restrict__ X, const float* __restrict__ DE,
                         const float* __restrict__ Wq, const float* __restrict__ Wk,
                         const float* __restrict__ Wv,
                         bf16* __restrict__ Xb, bf16* __restrict__ DEb,
                         bf16* __restrict__ WTb) {
    int bid = blockIdx.x;
    if (bid < 4352) {
        int i = bid * 256 + threadIdx.x;
        if (i < 1048576) {
            float4 v = reinterpret_cast<const float4*>(X)[i];
            bf16* d = Xb + 4 * i;
            d[0] = __float2bfloat16(v.x); d[1] = __float2bfloat16(v.y);
            d[2] = __float2bfloat16(v.z); d[3] = __float2bfloat16(v.w);
        } else {
            int j = i - 1048576;
            if (j < 65520) {
                float4 v = reinterpret_cast<const float4*>(DE)[j];
                bf16* d = DEb + 4 * j;
                d[0] = __float2bfloat16(v.x); d[1] = __float2bfloat16(v.y);
                d[2] = __float2bfloat16(v.z); d[3] = __float2bfloat16(v.w);
            }
        }
        return;
    }
    int t = bid - 4352;
    int proj = t >> 8;
    int rem = t & 255;
    const float* W = (proj == 0) ? Wq : (proj == 1) ? Wk : Wv;
    bf16* WT = WTb + (size_t)proj * (1024u * 1024u);
    __shared__ float tr[64][65];
    int tid = threadIdx.x;
    int col = tid & 63;
    int r4 = tid >> 6;
    int i0 = (rem & 15) * 64, o0 = (rem >> 4) * 64;
    for (int it = 0; it < 16; ++it) {
        int row = it * 4 + r4;
        tr[row][col] = W[(size_t)(i0 + row) * 1024 + o0 + col];
    }
    __syncthreads();
    for (int it = 0; it < 16; ++it) {
        int row = it * 4 + r4;
        WT[(size_t)(o0 + row) * 1024 + i0 + col] = __float2bfloat16(tr[col][row]);
    }
}

// ---------------------------------------------------------------------------
// Phase 1: QKV projection GEMM — r12 structure (reg-staged + T14 split);
// launch_bounds (256,3): grid is 768 = exactly 3 blocks/CU, so cap registers
// for 12 waves/CU co-residency (balanced, no 2-round tail).
// ---------------------------------------------------------------------------
__global__ __launch_bounds__(256, 3) void proj_gemm(
    const bf16* __restrict__ Xb, const bf16* __restrict__ WTb,
    const float* __restrict__ bq, const float* __restrict__ bk, const float* __restrict__ bv,
    bf16* __restrict__ Qb, bf16* __restrict__ Kb, bf16* __restrict__ VTb) {
    int proj = blockIdx.z;
    const bf16* W = WTb + (size_t)proj * (1024u * 1024u);
    const float* bias = (proj == 0) ? bq : (proj == 1) ? bk : bv;

    __shared__ bf16 XT[128][72];
    __shared__ bf16 WTt[128][72];

    int tid = threadIdx.x;
    int w = tid >> 6, lane = tid & 63, g = lane >> 4, li = lane & 15;
    int wr = w >> 1, wc = w & 1;
    int m0 = blockIdx.x * 128, n0 = blockIdx.y * 128;

    int srow = tid >> 3;          // 0..31
    int scol = (tid & 7) * 8;     // 0..56

    f32x4 acc[4][4];
    for (int mt = 0; mt < 4; mt++)
        for (int nt = 0; nt < 4; nt++) acc[mt][nt] = {0.f, 0.f, 0.f, 0.f};

    bf16x8 sx[4], swr[4];
    #pragma unroll
    for (int it = 0; it < 4; ++it) {
        int row = srow + 32 * it;
        sx[it]  = *reinterpret_cast<const bf16x8*>(Xb + (size_t)(m0 + row) * 1024 + scol);
        swr[it] = *reinterpret_cast<const bf16x8*>(W  + (size_t)(n0 + row) * 1024 + scol);
    }

    for (int ks = 0; ks < 16; ++ks) {
        #pragma unroll
        for (int it = 0; it < 4; ++it) {
            int row = srow + 32 * it;
            *reinterpret_cast<bf16x8*>(&XT[row][scol])  = sx[it];
            *reinterpret_cast<bf16x8*>(&WTt[row][scol]) = swr[it];
        }
        __syncthreads();
        if (ks < 15) {
            #pragma unroll
            for (int it = 0; it < 4; ++it) {
                int row = srow + 32 * it;
                sx[it]  = *reinterpret_cast<const bf16x8*>(
                    Xb + (size_t)(m0 + row) * 1024 + (ks + 1) * 64 + scol);
                swr[it] = *reinterpret_cast<const bf16x8*>(
                    W + (size_t)(n0 + row) * 1024 + (ks + 1) * 64 + scol);
            }
        }
        #pragma unroll
        for (int kk = 0; kk < 2; ++kk) {
            bf16x8 af[4], bfr[4];
            #pragma unroll
            for (int mt = 0; mt < 4; mt++)
                af[mt] = *reinterpret_cast<const bf16x8*>(&XT[64 * wr + 16 * mt + li][32 * kk + 8 * g]);
            #pragma unroll
            for (int nt = 0; nt < 4; nt++)
                bfr[nt] = *reinterpret_cast<const bf16x8*>(&WTt[64 * wc + 16 * nt + li][32 * kk + 8 * g]);
            #pragma unroll
            for (int mt = 0; mt < 4; mt++)
                #pragma unroll
                for (int nt = 0; nt < 4; nt++)
                    acc[mt][nt] = MFMA(af[mt], bfr[nt], acc[mt][nt]);
        }
        __syncthreads();
    }

    for (int mt = 0; mt < 4; mt++)
        for (int nt = 0; nt < 4; nt++) {
            int n = n0 + 64 * wc + 16 * nt + li;
            int h = n >> 6, d = n & 63;
            float bv_ = bias[n];
            for (int r = 0; r < 4; r++) {
                int m = m0 + 64 * wr + 16 * mt + 4 * g + r;
                int b = m >> 10, s = m & 1023;
                bf16 o = __float2bfloat16(acc[mt][nt][r] + bv_);
                if (proj == 0)      Qb[((size_t)(b * 16 + h) * 1024 + s) * 64 + d] = o;
                else if (proj == 1) Kb[((size_t)(b * 16 + h) * 1024 + s) * 64 + d] = o;
                else                VTb[((size_t)(b * 16 + h) * 64 + d) * 1024 + s] = o;
            }
        }
}

// ---------------------------------------------------------------------------
// Phase 2: fused attention v12 — r13 structure (in-register P transpose) +
// ka-frag dedupe: ka0/ka1 captured from the nt==gsel iteration of the QK^T
// loop (gsel hoisted to SGPR via readfirstlane -> uniform branch).
// ---------------------------------------------------------------------------
__global__ __launch_bounds__(512, 4) void attn_fused(
    const bf16* __restrict__ Qg, const bf16* __restrict__ Kg,
    const bf16* __restrict__ VTg, const bf16* __restrict__ DEb,
    const float* __restrict__ mask, float* __restrict__ out) {
    const int S = 1024, D = 64;
    const float C8 = 0.18033688011112042f;   // log2(e)/8
    int p_ = blockIdx.x;
    int idx = p_ >> 3;
    int bh = (p_ & 7) * 8 + (idx >> 3);      // 8 bh per XCD
    int qb = idx & 7;
    int b = bh >> 4, h = bh & 15;
    int L0 = qb * 128;

    int tid = threadIdx.x;
    int w = tid >> 6, lane = tid & 63, g = lane >> 4, li = lane & 15;

    __shared__ __align__(16) char smem[81664];
    bf16 (*Mb)[64] = reinterpret_cast<bf16(*)[64]>(smem + 81408);

    const char* Kh = (const char*)(Kg + (size_t)bh * S * D);
    const char* Vh = (const char*)(VTg + (size_t)bh * D * S);
    const char* DEc = (const char*)DEb;
    const float* maskb = mask + (size_t)b * S;

    int sw = (li & 7) << 4;
    int c0 = (16 * g) ^ sw;
    int c1 = (64 + 16 * g) ^ sw;
    const char* KbL = smem + li * 128;
    int gsel = (w < 4) ? (3 - w) : (7 - w);
    gsel = __builtin_amdgcn_readfirstlane(gsel);   // wave-uniform -> SGPR
    const char* Vb_ = smem + 8192 + li * 128;
    const char* Db_ = smem + 16384;

    int srow = tid >> 3;                       // 0..63
    int sc = 16 * ((lane & 7) ^ (lane >> 3));

    bf16x8 qa0, qa1;
    {
        const bf16* qrow = Qg + (size_t)bh * S * D + (size_t)(L0 + 16 * w + li) * D;
        qa0 = *reinterpret_cast<const bf16x8*>(qrow + 8 * g);
        qa1 = *reinterpret_cast<const bf16x8*>(qrow + 32 + 8 * g);
    }

    const char* qdb = smem + 40960 + 2688 * w + 170 * li - 8 * g;
    const char* kdb = smem + 62464 + 1176 * g + 32 * w + 2 * li + 30;
    char* qsp = smem + 40960 + 2688 * w + 168 * li + 8 * g;
    char* ksp = smem + 62464 + 296 * (16 * gsel + li) + ((w < 4) ? 0 : 128) + 8 * g;

    int de00 = L0 + 1984;
    int jb = de00 % 192;
    {
        gload16(Kh + (size_t)srow * 128 + sc, smem + w * 1024);
        gload16(Vh + (size_t)srow * 2048 + sc, smem + 8192 + w * 1024);
        #pragma unroll
        for (int c = 0; c < 3; ++c) {
            int pb = jb + 64 * c; if (pb >= 192) pb -= 192;
            gload16(DEc + (size_t)(de00 + 64 * c + srow) * 128 + sc,
                    smem + 16384 + pb * 128 + w * 1024);
        }
        if (tid < 64) Mb[0][tid] = __float2bfloat16(maskb[tid]);
    }

    f32x4 acc_o[4];
    for (int dt = 0; dt < 4; dt++) acc_o[dt] = {0.f, 0.f, 0.f, 0.f};
    float m_run = -1e30f, l_run = 0.f;

    __syncthreads();

    for (int kt = 0; kt < 16; ++kt) {
        int r0 = kt * 64;
        bool has_next = (kt < 15);
        int jbw = jb + 16 * w;

        if (kt) {
            gload16(Vh + (size_t)srow * 2048 + (size_t)r0 * 2 + sc, smem + 8192 + w * 1024);
        }

        __builtin_amdgcn_s_setprio(1);
        f32x4 s_acc[4];
        bf16x8 ka0, ka1;
        #pragma unroll
        for (int nt = 0; nt < 4; ++nt) {
            bf16x8 kb0 = *reinterpret_cast<const bf16x8*>(KbL + nt * 2048 + c0);
            bf16x8 kb1 = *reinterpret_cast<const bf16x8*>(KbL + nt * 2048 + c1);
            f32x4 z = {0.f, 0.f, 0.f, 0.f};
            z = MFMA(kb0, qa0, z);
            z = MFMA(kb1, qa1, z);
            s_acc[nt] = z;
            if (nt == gsel) { ka0 = kb0; ka1 = kb1; }   // uniform branch (SGPR)
        }
        {
            #pragma unroll
            for (int jt = 0; jt < 5; ++jt) {
                int x = jbw + 16 * jt + li;
                if (x >= 192) x -= 192;
                const char* dp = Db_ + x * 128;
                bf16x8 d0 = *reinterpret_cast<const bf16x8*>(dp + c0);
                bf16x8 d1 = *reinterpret_cast<const bf16x8*>(dp + c1);
                f32x4 aq = {0.f, 0.f, 0.f, 0.f};
                aq = MFMA(d0, qa0, aq);
                aq = MFMA(d1, qa1, aq);
                f32x4 ak = {0.f, 0.f, 0.f, 0.f};
                ak = MFMA(d0, ka0, ak);
                ak = MFMA(d1, ka1, ak);
                u32x2 uq = {pk2(aq[0], aq[1]), pk2(aq[2], aq[3])};
                *reinterpret_cast<u32x2*>(qsp + 32 * jt) = uq;
                u32x2 uk = {pk2(ak[0], ak[1]), pk2(ak[2], ak[3])};
                *reinterpret_cast<u32x2*>(ksp + 32 * jt) = uk;
            }
        }
        __builtin_amdgcn_s_setprio(0);
        __syncthreads();

        float sM;
        if (has_next) {
            int r0n = r0 + 64;
            int dlo = de00 - 64 * (kt + 1);
            int jbN = (jb >= 64) ? jb - 64 : jb + 128;
            gload16(Kh + (size_t)(r0n + srow) * 128 + sc, smem + w * 1024);
            gload16(DEc + (size_t)(dlo + srow) * 128 + sc,
                    smem + 16384 + jbN * 128 + w * 1024);
            if (tid < 64) sM = maskb[r0n + tid];
            jb = jbN;
        }

        float u[4][4];
        float lmax = -1e30f;
        #pragma unroll
        for (int nt = 0; nt < 4; ++nt) {
            unsigned long long mraw =
                *reinterpret_cast<const unsigned long long*>(&Mb[kt & 1][16 * nt + 4 * g]);
            #pragma unroll
            for (int r = 0; r < 4; ++r) {
                float qd = bf2f(*reinterpret_cast<const bf16*>(qdb + (126 - 32 * nt - 2 * r)));
                float kd = bf2f(*reinterpret_cast<const bf16*>(kdb + (4736 * nt + 294 * r)));
                float mk = __builtin_bit_cast(float,
                    (unsigned)((mraw >> (16 * r)) & 0xffffull) << 16);
                float uu = s_acc[nt][r] + qd + kd;
                uu = __builtin_fmaf(mk, 8.0f, uu);
                u[nt][r] = uu;
                lmax = fmaxf(lmax, uu);
            }
        }
        float tm = quad_max(lmax);
        bool noskip = !__all(tm <= m_run);
        float scl = 1.0f;
        if (noskip) {
            float mnew = fmaxf(m_run, tm);
            scl = exp2f((m_run - mnew) * C8);
            m_run = mnew;
        }
        float nmc = -m_run * C8;
        float pv[4][4];
        #pragma unroll
        for (int nt = 0; nt < 4; ++nt)
            #pragma unroll
            for (int r = 0; r < 4; ++r)
                pv[nt][r] = exp2f(__builtin_fmaf(u[nt][r], C8, nmc));
        float t0 = (pv[0][0] + pv[0][1]) + (pv[0][2] + pv[0][3]);
        float t1 = (pv[1][0] + pv[1][1]) + (pv[1][2] + pv[1][3]);
        float t2 = (pv[2][0] + pv[2][1]) + (pv[2][2] + pv[2][3]);
        float t3 = (pv[3][0] + pv[3][1]) + (pv[3][2] + pv[3][3]);
        float qs = quad_sum((t0 + t1) + (t2 + t3));
        if (noskip) {
            l_run = l_run * scl + qs;
            #pragma unroll
            for (int dt = 0; dt < 4; dt++) acc_o[dt] *= scl;
        } else {
            l_run += qs;
        }

        // ---- P^T -> PV B-frags fully in-register (verified r13) ----
        unsigned x0 = pk2(pv[0][0], pv[0][1]), x1 = pk2(pv[0][2], pv[0][3]);
        unsigned z0 = pk2(pv[1][0], pv[1][1]), z1 = pk2(pv[1][2], pv[1][3]);
        unsigned y0 = pk2(pv[2][0], pv[2][1]), y1 = pk2(pv[2][2], pv[2][3]);
        unsigned w0 = pk2(pv[3][0], pv[3][1]), w1 = pk2(pv[3][2], pv[3][3]);
        sw32(x0, z0); sw32(x1, z1);
        sw16(x0, z0); sw16(x1, z1);
        sw32(y0, w0); sw32(y1, w1);
        sw16(y0, w0); sw16(y1, w1);
        u32x4 f0v = {x0, x1, z0, z1};
        u32x4 f1v = {y0, y1, w0, w1};
        bf16x8 pb0 = __builtin_bit_cast(bf16x8, f0v);
        bf16x8 pb1 = __builtin_bit_cast(bf16x8, f1v);

        __builtin_amdgcn_s_setprio(1);
        #pragma unroll
        for (int dt = 0; dt < 4; dt++) {
            bf16x8 va0 = *reinterpret_cast<const bf16x8*>(Vb_ + dt * 2048 + c0);
            bf16x8 va1 = *reinterpret_cast<const bf16x8*>(Vb_ + dt * 2048 + c1);
            acc_o[dt] = MFMA(va0, pb0, acc_o[dt]);
            acc_o[dt] = MFMA(va1, pb1, acc_o[dt]);
        }
        __builtin_amdgcn_s_setprio(0);

        if (has_next && tid < 64) Mb[(kt + 1) & 1][tid] = __float2bfloat16(sM);
        __syncthreads();
    }

    float inv = 1.0f / l_run;
    float (*OT)[68] = reinterpret_cast<float (*)[68]>(smem);
    #pragma unroll
    for (int dt = 0; dt < 4; dt++)
        #pragma unroll
        for (int r = 0; r < 4; r++)
            OT[16 * w + li][16 * dt + 4 * g + r] = acc_o[dt][r] * inv;
    __syncthreads();
    {
        int q = tid >> 2, seg = tid & 3;
        float* gout = out + ((size_t)(b * 1024 + L0 + q)) * 1024 + h * 64 + 16 * seg;
        #pragma unroll
        for (int j = 0; j < 4; ++j)
            *reinterpret_cast<float4*>(gout + 4 * j) =
                *reinterpret_cast<const float4*>(&OT[q][16 * seg + 4 * j]);
    }
}

// ---------------------------------------------------------------------------
extern "C" void kernel_launch(void* const* d_in, const int* in_sizes, int n_in,
                              void* d_out, int out_size, void* d_ws, size_t ws_size,
                              hipStream_t stream) {
    const float* X   = (const float*)d_in[0];
    const float* msk = (const float*)d_in[1];
    const float* Wq  = (const float*)d_in[2];
    const float* bq  = (const float*)d_in[3];
    const float* Wk  = (const float*)d_in[4];
    const float* bk  = (const float*)d_in[5];
    const float* Wv  = (const float*)d_in[6];
    const float* bv  = (const float*)d_in[7];
    const float* DE  = (const float*)d_in[8];
    float* out = (float*)d_out;

    bf16* ws  = (bf16*)d_ws;
    bf16* Xb  = ws;              // 4194304
    bf16* WTb = ws + 4194304;    // 3145728
    bf16* DEb = ws + 7340032;    // 262144
    bf16* Qb  = ws + 7602176;    // 4194304
    bf16* Kb  = ws + 11796480;   // 4194304
    bf16* VTb = ws + 15990784;   // 4194304

    prep_all<<<5120, 256, 0, stream>>>(X, DE, Wq, Wk, Wv, Xb, DEb, WTb);
    proj_gemm<<<dim3(32, 8, 3), 256, 0, stream>>>(Xb, WTb, bq, bk, bv, Qb, Kb, VTb);
    attn_fused<<<512, 512, 0, stream>>>(Qb, Kb, VTb, DEb, msk, out);
}

// Round 15
// 130.803 us; speedup vs baseline: 1.0548x; 1.0548x over previous
//
#include <hip/hip_runtime.h>
#include <hip/hip_bf16.h>

typedef __hip_bfloat16 bf16;
typedef __attribute__((ext_vector_type(8))) short bf16x8;   // 8 bf16 = 4 VGPRs (MFMA A/B frag)
typedef __attribute__((ext_vector_type(4))) float f32x4;    // MFMA C/D frag
typedef __attribute__((ext_vector_type(2))) unsigned int u32x2;
typedef __attribute__((ext_vector_type(4))) unsigned int u32x4;

#define MFMA(a, b, c) __builtin_amdgcn_mfma_f32_16x16x32_bf16((a), (b), (c), 0, 0, 0)

static __device__ __forceinline__ float bf2f(bf16 b) { return __bfloat162float(b); }

// Packed f32->bf16 (truncation) via single v_perm_b32 (passed r7..r14).
static __device__ __forceinline__ unsigned pk2(float a, float b) {
    return __builtin_amdgcn_perm(__builtin_bit_cast(unsigned, b),
                                 __builtin_bit_cast(unsigned, a), 0x07060302u);
}

// Quad-row swaps (rows = 16-lane groups). Semantics pinned by r13's working
// in-register P transpose: sw32 exchanges a.rows{2,3} <-> b.rows{0,1};
// sw16 exchanges a.odd-rows <-> b.even-rows.
static __device__ __forceinline__ void sw32(unsigned& a, unsigned& b) {
    u32x2 r = __builtin_amdgcn_permlane32_swap(a, b, false, false);
    a = r[0]; b = r[1];
}
static __device__ __forceinline__ void sw16(unsigned& a, unsigned& b) {
    u32x2 r = __builtin_amdgcn_permlane16_swap(a, b, false, false);
    a = r[0]; b = r[1];
}

// Quad reductions over lanes {li, li+16, li+32, li+48} on the VALU pipe
// (replaces __shfl_xor's ds_swizzle ops on the binding LDS pipe).
static __device__ __forceinline__ float quad_max(float x) {
    unsigned a = __builtin_bit_cast(unsigned, x), b = a;
    sw32(a, b);
    float y = fmaxf(__builtin_bit_cast(float, a), __builtin_bit_cast(float, b));
    unsigned c = __builtin_bit_cast(unsigned, y), d = c;
    sw16(c, d);
    return fmaxf(__builtin_bit_cast(float, c), __builtin_bit_cast(float, d));
}
static __device__ __forceinline__ float quad_sum(float x) {
    unsigned a = __builtin_bit_cast(unsigned, x), b = a;
    sw32(a, b);
    float y = __builtin_bit_cast(float, a) + __builtin_bit_cast(float, b);
    unsigned c = __builtin_bit_cast(unsigned, y), d = c;
    sw16(c, d);
    return __builtin_bit_cast(float, c) + __builtin_bit_cast(float, d);
}

// Async global->LDS DMA, 16B per lane. LDS dest = wave-uniform base + lane*16.
static __device__ __forceinline__ void gload16(const void* g, void* l) {
    __builtin_amdgcn_global_load_lds(
        (const __attribute__((address_space(1))) void*)g,
        (__attribute__((address_space(3))) void*)l, 16, 0, 0);
}

// ---------------------------------------------------------------------------
// Phase 0 (merged): blocks [0,4352): convert X + dist_emb to bf16;
// blocks [4352,5120): transpose Wq/Wk/Wv f32 [in][out] -> WT bf16 [out][in].
// ---------------------------------------------------------------------------
__global__ void prep_all(const float* __restrict__ X, const float* __restrict__ DE,
                         const float* __restrict__ Wq, const float* __restrict__ Wk,
                         const float* __restrict__ Wv,
                         bf16* __restrict__ Xb, bf16* __restrict__ DEb,
                         bf16* __restrict__ WTb) {
    int bid = blockIdx.x;
    if (bid < 4352) {
        int i = bid * 256 + threadIdx.x;
        if (i < 1048576) {
            float4 v = reinterpret_cast<const float4*>(X)[i];
            bf16* d = Xb + 4 * i;
            d[0] = __float2bfloat16(v.x); d[1] = __float2bfloat16(v.y);
            d[2] = __float2bfloat16(v.z); d[3] = __float2bfloat16(v.w);
        } else {
            int j = i - 1048576;
            if (j < 65520) {
                float4 v = reinterpret_cast<const float4*>(DE)[j];
                bf16* d = DEb + 4 * j;
                d[0] = __float2bfloat16(v.x); d[1] = __float2bfloat16(v.y);
                d[2] = __float2bfloat16(v.z); d[3] = __float2bfloat16(v.w);
            }
        }
        return;
    }
    int t = bid - 4352;
    int proj = t >> 8;
    int rem = t & 255;
    const float* W = (proj == 0) ? Wq : (proj == 1) ? Wk : Wv;
    bf16* WT = WTb + (size_t)proj * (1024u * 1024u);
    __shared__ float tr[64][65];
    int tid = threadIdx.x;
    int col = tid & 63;
    int r4 = tid >> 6;
    int i0 = (rem & 15) * 64, o0 = (rem >> 4) * 64;
    for (int it = 0; it < 16; ++it) {
        int row = it * 4 + r4;
        tr[row][col] = W[(size_t)(i0 + row) * 1024 + o0 + col];
    }
    __syncthreads();
    for (int it = 0; it < 16; ++it) {
        int row = it * 4 + r4;
        WT[(size_t)(o0 + row) * 1024 + i0 + col] = __float2bfloat16(tr[col][row]);
    }
}

// ---------------------------------------------------------------------------
// Phase 1: QKV projection GEMM — r12 structure (reg-staged + T14 split),
// launch_bounds (256,3) for 3-block/CU co-residency on the 768-tile grid.
// ---------------------------------------------------------------------------
__global__ __launch_bounds__(256, 3) void proj_gemm(
    const bf16* __restrict__ Xb, const bf16* __restrict__ WTb,
    const float* __restrict__ bq, const float* __restrict__ bk, const float* __restrict__ bv,
    bf16* __restrict__ Qb, bf16* __restrict__ Kb, bf16* __restrict__ VTb) {
    int proj = blockIdx.z;
    const bf16* W = WTb + (size_t)proj * (1024u * 1024u);
    const float* bias = (proj == 0) ? bq : (proj == 1) ? bk : bv;

    __shared__ bf16 XT[128][72];
    __shared__ bf16 WTt[128][72];

    int tid = threadIdx.x;
    int w = tid >> 6, lane = tid & 63, g = lane >> 4, li = lane & 15;
    int wr = w >> 1, wc = w & 1;
    int m0 = blockIdx.x * 128, n0 = blockIdx.y * 128;

    int srow = tid >> 3;          // 0..31
    int scol = (tid & 7) * 8;     // 0..56

    f32x4 acc[4][4];
    for (int mt = 0; mt < 4; mt++)
        for (int nt = 0; nt < 4; nt++) acc[mt][nt] = {0.f, 0.f, 0.f, 0.f};

    bf16x8 sx[4], swr[4];
    #pragma unroll
    for (int it = 0; it < 4; ++it) {
        int row = srow + 32 * it;
        sx[it]  = *reinterpret_cast<const bf16x8*>(Xb + (size_t)(m0 + row) * 1024 + scol);
        swr[it] = *reinterpret_cast<const bf16x8*>(W  + (size_t)(n0 + row) * 1024 + scol);
    }

    for (int ks = 0; ks < 16; ++ks) {
        #pragma unroll
        for (int it = 0; it < 4; ++it) {
            int row = srow + 32 * it;
            *reinterpret_cast<bf16x8*>(&XT[row][scol])  = sx[it];
            *reinterpret_cast<bf16x8*>(&WTt[row][scol]) = swr[it];
        }
        __syncthreads();
        if (ks < 15) {
            #pragma unroll
            for (int it = 0; it < 4; ++it) {
                int row = srow + 32 * it;
                sx[it]  = *reinterpret_cast<const bf16x8*>(
                    Xb + (size_t)(m0 + row) * 1024 + (ks + 1) * 64 + scol);
                swr[it] = *reinterpret_cast<const bf16x8*>(
                    W + (size_t)(n0 + row) * 1024 + (ks + 1) * 64 + scol);
            }
        }
        #pragma unroll
        for (int kk = 0; kk < 2; ++kk) {
            bf16x8 af[4], bfr[4];
            #pragma unroll
            for (int mt = 0; mt < 4; mt++)
                af[mt] = *reinterpret_cast<const bf16x8*>(&XT[64 * wr + 16 * mt + li][32 * kk + 8 * g]);
            #pragma unroll
            for (int nt = 0; nt < 4; nt++)
                bfr[nt] = *reinterpret_cast<const bf16x8*>(&WTt[64 * wc + 16 * nt + li][32 * kk + 8 * g]);
            #pragma unroll
            for (int mt = 0; mt < 4; mt++)
                #pragma unroll
                for (int nt = 0; nt < 4; nt++)
                    acc[mt][nt] = MFMA(af[mt], bfr[nt], acc[mt][nt]);
        }
        __syncthreads();
    }

    for (int mt = 0; mt < 4; mt++)
        for (int nt = 0; nt < 4; nt++) {
            int n = n0 + 64 * wc + 16 * nt + li;
            int h = n >> 6, d = n & 63;
            float bv_ = bias[n];
            for (int r = 0; r < 4; r++) {
                int m = m0 + 64 * wr + 16 * mt + 4 * g + r;
                int b = m >> 10, s = m & 1023;
                bf16 o = __float2bfloat16(acc[mt][nt][r] + bv_);
                if (proj == 0)      Qb[((size_t)(b * 16 + h) * 1024 + s) * 64 + d] = o;
                else if (proj == 1) Kb[((size_t)(b * 16 + h) * 1024 + s) * 64 + d] = o;
                else                VTb[((size_t)(b * 16 + h) * 64 + d) * 1024 + s] = o;
            }
        }
}

// ---------------------------------------------------------------------------
// Phase 2: fused attention v13 — r13 structure (separate ka reads restored),
// with quad reductions moved to the VALU pipe via permlane swaps.
// ---------------------------------------------------------------------------
__global__ __launch_bounds__(512, 4) void attn_fused(
    const bf16* __restrict__ Qg, const bf16* __restrict__ Kg,
    const bf16* __restrict__ VTg, const bf16* __restrict__ DEb,
    const float* __restrict__ mask, float* __restrict__ out) {
    const int S = 1024, D = 64;
    const float C8 = 0.18033688011112042f;   // log2(e)/8
    int p_ = blockIdx.x;
    int idx = p_ >> 3;
    int bh = (p_ & 7) * 8 + (idx >> 3);      // 8 bh per XCD
    int qb = idx & 7;
    int b = bh >> 4, h = bh & 15;
    int L0 = qb * 128;

    int tid = threadIdx.x;
    int w = tid >> 6, lane = tid & 63, g = lane >> 4, li = lane & 15;

    __shared__ __align__(16) char smem[81664];
    bf16 (*Mb)[64] = reinterpret_cast<bf16(*)[64]>(smem + 81408);

    const char* Kh = (const char*)(Kg + (size_t)bh * S * D);
    const char* Vh = (const char*)(VTg + (size_t)bh * D * S);
    const char* DEc = (const char*)DEb;
    const float* maskb = mask + (size_t)b * S;

    int sw = (li & 7) << 4;
    int c0 = (16 * g) ^ sw;
    int c1 = (64 + 16 * g) ^ sw;
    const char* KbL = smem + li * 128;
    int gsel = (w < 4) ? (3 - w) : (7 - w);
    const char* KaL = smem + (16 * gsel + li) * 128;
    const char* Vb_ = smem + 8192 + li * 128;
    const char* Db_ = smem + 16384;

    int srow = tid >> 3;                       // 0..63
    int sc = 16 * ((lane & 7) ^ (lane >> 3));

    bf16x8 qa0, qa1;
    {
        const bf16* qrow = Qg + (size_t)bh * S * D + (size_t)(L0 + 16 * w + li) * D;
        qa0 = *reinterpret_cast<const bf16x8*>(qrow + 8 * g);
        qa1 = *reinterpret_cast<const bf16x8*>(qrow + 32 + 8 * g);
    }

    const char* qdb = smem + 40960 + 2688 * w + 170 * li - 8 * g;
    const char* kdb = smem + 62464 + 1176 * g + 32 * w + 2 * li + 30;
    char* qsp = smem + 40960 + 2688 * w + 168 * li + 8 * g;
    char* ksp = smem + 62464 + 296 * (16 * gsel + li) + ((w < 4) ? 0 : 128) + 8 * g;

    int de00 = L0 + 1984;
    int jb = de00 % 192;
    {
        gload16(Kh + (size_t)srow * 128 + sc, smem + w * 1024);
        gload16(Vh + (size_t)srow * 2048 + sc, smem + 8192 + w * 1024);
        #pragma unroll
        for (int c = 0; c < 3; ++c) {
            int pb = jb + 64 * c; if (pb >= 192) pb -= 192;
            gload16(DEc + (size_t)(de00 + 64 * c + srow) * 128 + sc,
                    smem + 16384 + pb * 128 + w * 1024);
        }
        if (tid < 64) Mb[0][tid] = __float2bfloat16(maskb[tid]);
    }

    f32x4 acc_o[4];
    for (int dt = 0; dt < 4; dt++) acc_o[dt] = {0.f, 0.f, 0.f, 0.f};
    float m_run = -1e30f, l_run = 0.f;

    __syncthreads();

    for (int kt = 0; kt < 16; ++kt) {
        int r0 = kt * 64;
        bool has_next = (kt < 15);
        int jbw = jb + 16 * w;

        if (kt) {
            gload16(Vh + (size_t)srow * 2048 + (size_t)r0 * 2 + sc, smem + 8192 + w * 1024);
        }

        __builtin_amdgcn_s_setprio(1);
        f32x4 s_acc[4];
        #pragma unroll
        for (int nt = 0; nt < 4; ++nt) {
            bf16x8 kb0 = *reinterpret_cast<const bf16x8*>(KbL + nt * 2048 + c0);
            bf16x8 kb1 = *reinterpret_cast<const bf16x8*>(KbL + nt * 2048 + c1);
            f32x4 z = {0.f, 0.f, 0.f, 0.f};
            z = MFMA(kb0, qa0, z);
            z = MFMA(kb1, qa1, z);
            s_acc[nt] = z;
        }
        {
            bf16x8 ka0 = *reinterpret_cast<const bf16x8*>(KaL + c0);
            bf16x8 ka1 = *reinterpret_cast<const bf16x8*>(KaL + c1);
            #pragma unroll
            for (int jt = 0; jt < 5; ++jt) {
                int x = jbw + 16 * jt + li;
                if (x >= 192) x -= 192;
                const char* dp = Db_ + x * 128;
                bf16x8 d0 = *reinterpret_cast<const bf16x8*>(dp + c0);
                bf16x8 d1 = *reinterpret_cast<const bf16x8*>(dp + c1);
                f32x4 aq = {0.f, 0.f, 0.f, 0.f};
                aq = MFMA(d0, qa0, aq);
                aq = MFMA(d1, qa1, aq);
                f32x4 ak = {0.f, 0.f, 0.f, 0.f};
                ak = MFMA(d0, ka0, ak);
                ak = MFMA(d1, ka1, ak);
                u32x2 uq = {pk2(aq[0], aq[1]), pk2(aq[2], aq[3])};
                *reinterpret_cast<u32x2*>(qsp + 32 * jt) = uq;
                u32x2 uk = {pk2(ak[0], ak[1]), pk2(ak[2], ak[3])};
                *reinterpret_cast<u32x2*>(ksp + 32 * jt) = uk;
            }
        }
        __builtin_amdgcn_s_setprio(0);
        __syncthreads();

        float sM;
        if (has_next) {
            int r0n = r0 + 64;
            int dlo = de00 - 64 * (kt + 1);
            int jbN = (jb >= 64) ? jb - 64 : jb + 128;
            gload16(Kh + (size_t)(r0n + srow) * 128 + sc, smem + w * 1024);
            gload16(DEc + (size_t)(dlo + srow) * 128 + sc,
                    smem + 16384 + jbN * 128 + w * 1024);
            if (tid < 64) sM = maskb[r0n + tid];
            jb = jbN;
        }

        float u[4][4];
        float lmax = -1e30f;
        #pragma unroll
        for (int nt = 0; nt < 4; ++nt) {
            unsigned long long mraw =
                *reinterpret_cast<const unsigned long long*>(&Mb[kt & 1][16 * nt + 4 * g]);
            #pragma unroll
            for (int r = 0; r < 4; ++r) {
                float qd = bf2f(*reinterpret_cast<const bf16*>(qdb + (126 - 32 * nt - 2 * r)));
                float kd = bf2f(*reinterpret_cast<const bf16*>(kdb + (4736 * nt + 294 * r)));
                float mk = __builtin_bit_cast(float,
                    (unsigned)((mraw >> (16 * r)) & 0xffffull) << 16);
                float uu = s_acc[nt][r] + qd + kd;
                uu = __builtin_fmaf(mk, 8.0f, uu);
                u[nt][r] = uu;
                lmax = fmaxf(lmax, uu);
            }
        }
        float tm = quad_max(lmax);
        bool noskip = !__all(tm <= m_run);
        float scl = 1.0f;
        if (noskip) {
            float mnew = fmaxf(m_run, tm);
            scl = exp2f((m_run - mnew) * C8);
            m_run = mnew;
        }
        float nmc = -m_run * C8;
        float pv[4][4];
        #pragma unroll
        for (int nt = 0; nt < 4; ++nt)
            #pragma unroll
            for (int r = 0; r < 4; ++r)
                pv[nt][r] = exp2f(__builtin_fmaf(u[nt][r], C8, nmc));
        float t0 = (pv[0][0] + pv[0][1]) + (pv[0][2] + pv[0][3]);
        float t1 = (pv[1][0] + pv[1][1]) + (pv[1][2] + pv[1][3]);
        float t2 = (pv[2][0] + pv[2][1]) + (pv[2][2] + pv[2][3]);
        float t3 = (pv[3][0] + pv[3][1]) + (pv[3][2] + pv[3][3]);
        float qs = quad_sum((t0 + t1) + (t2 + t3));
        if (noskip) {
            l_run = l_run * scl + qs;
            #pragma unroll
            for (int dt = 0; dt < 4; dt++) acc_o[dt] *= scl;
        } else {
            l_run += qs;
        }

        // ---- P^T -> PV B-frags fully in-register (verified r13) ----
        unsigned x0 = pk2(pv[0][0], pv[0][1]), x1 = pk2(pv[0][2], pv[0][3]);
        unsigned z0 = pk2(pv[1][0], pv[1][1]), z1 = pk2(pv[1][2], pv[1][3]);
        unsigned y0 = pk2(pv[2][0], pv[2][1]), y1 = pk2(pv[2][2], pv[2][3]);
        unsigned w0 = pk2(pv[3][0], pv[3][1]), w1 = pk2(pv[3][2], pv[3][3]);
        sw32(x0, z0); sw32(x1, z1);
        sw16(x0, z0); sw16(x1, z1);
        sw32(y0, w0); sw32(y1, w1);
        sw16(y0, w0); sw16(y1, w1);
        u32x4 f0v = {x0, x1, z0, z1};
        u32x4 f1v = {y0, y1, w0, w1};
        bf16x8 pb0 = __builtin_bit_cast(bf16x8, f0v);
        bf16x8 pb1 = __builtin_bit_cast(bf16x8, f1v);

        __builtin_amdgcn_s_setprio(1);
        #pragma unroll
        for (int dt = 0; dt < 4; dt++) {
            bf16x8 va0 = *reinterpret_cast<const bf16x8*>(Vb_ + dt * 2048 + c0);
            bf16x8 va1 = *reinterpret_cast<const bf16x8*>(Vb_ + dt * 2048 + c1);
            acc_o[dt] = MFMA(va0, pb0, acc_o[dt]);
            acc_o[dt] = MFMA(va1, pb1, acc_o[dt]);
        }
        __builtin_amdgcn_s_setprio(0);

        if (has_next && tid < 64) Mb[(kt + 1) & 1][tid] = __float2bfloat16(sM);
        __syncthreads();
    }

    float inv = 1.0f / l_run;
    float (*OT)[68] = reinterpret_cast<float (*)[68]>(smem);
    #pragma unroll
    for (int dt = 0; dt < 4; dt++)
        #pragma unroll
        for (int r = 0; r < 4; r++)
            OT[16 * w + li][16 * dt + 4 * g + r] = acc_o[dt][r] * inv;
    __syncthreads();
    {
        int q = tid >> 2, seg = tid & 3;
        float* gout = out + ((size_t)(b * 1024 + L0 + q)) * 1024 + h * 64 + 16 * seg;
        #pragma unroll
        for (int j = 0; j < 4; ++j)
            *reinterpret_cast<float4*>(gout + 4 * j) =
                *reinterpret_cast<const float4*>(&OT[q][16 * seg + 4 * j]);
    }
}

// ---------------------------------------------------------------------------
extern "C" void kernel_launch(void* const* d_in, const int* in_sizes, int n_in,
                              void* d_out, int out_size, void* d_ws, size_t ws_size,
                              hipStream_t stream) {
    const float* X   = (const float*)d_in[0];
    const float* msk = (const float*)d_in[1];
    const float* Wq  = (const float*)d_in[2];
    const float* bq  = (const float*)d_in[3];
    const float* Wk  = (const float*)d_in[4];
    const float* bk  = (const float*)d_in[5];
    const float* Wv  = (const float*)d_in[6];
    const float* bv  = (const float*)d_in[7];
    const float* DE  = (const float*)d_in[8];
    float* out = (float*)d_out;

    bf16* ws  = (bf16*)d_ws;
    bf16* Xb  = ws;              // 4194304
    bf16* WTb = ws + 4194304;    // 3145728
    bf16* DEb = ws + 7340032;    // 262144
    bf16* Qb  = ws + 7602176;    // 4194304
    bf16* Kb  = ws + 11796480;   // 4194304
    bf16* VTb = ws + 15990784;   // 4194304

    prep_all<<<5120, 256, 0, stream>>>(X, DE, Wq, Wk, Wv, Xb, DEb, WTb);
    proj_gemm<<<dim3(32, 8, 3), 256, 0, stream>>>(Xb, WTb, bq, bk, bv, Qb, Kb, VTb);
    attn_fused<<<512, 512, 0, stream>>>(Qb, Kb, VTb, DEb, msk, out);
}

// Round 16
// 129.210 us; speedup vs baseline: 1.0678x; 1.0123x over previous
//
#include <hip/hip_runtime.h>
#include <hip/hip_bf16.h>

typedef __hip_bfloat16 bf16;
typedef __attribute__((ext_vector_type(8))) short bf16x8;   // 8 bf16 = 4 VGPRs (MFMA A/B frag)
typedef __attribute__((ext_vector_type(4))) float f32x4;    // MFMA C/D frag
typedef __attribute__((ext_vector_type(2))) unsigned int u32x2;
typedef __attribute__((ext_vector_type(4))) unsigned int u32x4;

#define MFMA(a, b, c) __builtin_amdgcn_mfma_f32_16x16x32_bf16((a), (b), (c), 0, 0, 0)

static __device__ __forceinline__ float bf2f(bf16 b) { return __bfloat162float(b); }

// Packed f32->bf16 (truncation) via single v_perm_b32 (passed r7..r15).
static __device__ __forceinline__ unsigned pk2(float a, float b) {
    return __builtin_amdgcn_perm(__builtin_bit_cast(unsigned, b),
                                 __builtin_bit_cast(unsigned, a), 0x07060302u);
}

// Quad-row swaps (rows = 16-lane groups). Semantics pinned by r13's working
// in-register P transpose: sw32 exchanges a.rows{2,3} <-> b.rows{0,1};
// sw16 exchanges a.odd-rows <-> b.even-rows.
static __device__ __forceinline__ void sw32(unsigned& a, unsigned& b) {
    u32x2 r = __builtin_amdgcn_permlane32_swap(a, b, false, false);
    a = r[0]; b = r[1];
}
static __device__ __forceinline__ void sw16(unsigned& a, unsigned& b) {
    u32x2 r = __builtin_amdgcn_permlane16_swap(a, b, false, false);
    a = r[0]; b = r[1];
}

// Quad reductions over lanes {li, li+16, li+32, li+48} on the VALU pipe
// (replaces __shfl_xor's ds_swizzle ops on the binding LDS pipe) — r15 win.
static __device__ __forceinline__ float quad_max(float x) {
    unsigned a = __builtin_bit_cast(unsigned, x), b = a;
    sw32(a, b);
    float y = fmaxf(__builtin_bit_cast(float, a), __builtin_bit_cast(float, b));
    unsigned c = __builtin_bit_cast(unsigned, y), d = c;
    sw16(c, d);
    return fmaxf(__builtin_bit_cast(float, c), __builtin_bit_cast(float, d));
}
static __device__ __forceinline__ float quad_sum(float x) {
    unsigned a = __builtin_bit_cast(unsigned, x), b = a;
    sw32(a, b);
    float y = __builtin_bit_cast(float, a) + __builtin_bit_cast(float, b);
    unsigned c = __builtin_bit_cast(unsigned, y), d = c;
    sw16(c, d);
    return __builtin_bit_cast(float, c) + __builtin_bit_cast(float, d);
}

// Async global->LDS DMA, 16B per lane. LDS dest = wave-uniform base + lane*16.
static __device__ __forceinline__ void gload16(const void* g, void* l) {
    __builtin_amdgcn_global_load_lds(
        (const __attribute__((address_space(1))) void*)g,
        (__attribute__((address_space(3))) void*)l, 16, 0, 0);
}

// ---------------------------------------------------------------------------
// Phase 0 (merged): blocks [0,4352): convert X + dist_emb to bf16;
// blocks [4352,5120): transpose Wq/Wk/Wv f32 [in][out] -> WT bf16 [out][in].
// ---------------------------------------------------------------------------
__global__ void prep_all(const float* __restrict__ X, const float* __restrict__ DE,
                         const float* __restrict__ Wq, const float* __restrict__ Wk,
                         const float* __restrict__ Wv,
                         bf16* __restrict__ Xb, bf16* __restrict__ DEb,
                         bf16* __restrict__ WTb) {
    int bid = blockIdx.x;
    if (bid < 4352) {
        int i = bid * 256 + threadIdx.x;
        if (i < 1048576) {
            float4 v = reinterpret_cast<const float4*>(X)[i];
            bf16* d = Xb + 4 * i;
            d[0] = __float2bfloat16(v.x); d[1] = __float2bfloat16(v.y);
            d[2] = __float2bfloat16(v.z); d[3] = __float2bfloat16(v.w);
        } else {
            int j = i - 1048576;
            if (j < 65520) {
                float4 v = reinterpret_cast<const float4*>(DE)[j];
                bf16* d = DEb + 4 * j;
                d[0] = __float2bfloat16(v.x); d[1] = __float2bfloat16(v.y);
                d[2] = __float2bfloat16(v.z); d[3] = __float2bfloat16(v.w);
            }
        }
        return;
    }
    int t = bid - 4352;
    int proj = t >> 8;
    int rem = t & 255;
    const float* W = (proj == 0) ? Wq : (proj == 1) ? Wk : Wv;
    bf16* WT = WTb + (size_t)proj * (1024u * 1024u);
    __shared__ float tr[64][65];
    int tid = threadIdx.x;
    int col = tid & 63;
    int r4 = tid >> 6;
    int i0 = (rem & 15) * 64, o0 = (rem >> 4) * 64;
    for (int it = 0; it < 16; ++it) {
        int row = it * 4 + r4;
        tr[row][col] = W[(size_t)(i0 + row) * 1024 + o0 + col];
    }
    __syncthreads();
    for (int it = 0; it < 16; ++it) {
        int row = it * 4 + r4;
        WT[(size_t)(o0 + row) * 1024 + i0 + col] = __float2bfloat16(tr[col][row]);
    }
}

// ---------------------------------------------------------------------------
// Phase 1: QKV projection GEMM — r12 structure (reg-staged + T14 split),
// launch_bounds (256,3) for 3-block/CU co-residency on the 768-tile grid.
// ---------------------------------------------------------------------------
__global__ __launch_bounds__(256, 3) void proj_gemm(
    const bf16* __restrict__ Xb, const bf16* __restrict__ WTb,
    const float* __restrict__ bq, const float* __restrict__ bk, const float* __restrict__ bv,
    bf16* __restrict__ Qb, bf16* __restrict__ Kb, bf16* __restrict__ VTb) {
    int proj = blockIdx.z;
    const bf16* W = WTb + (size_t)proj * (1024u * 1024u);
    const float* bias = (proj == 0) ? bq : (proj == 1) ? bk : bv;

    __shared__ bf16 XT[128][72];
    __shared__ bf16 WTt[128][72];

    int tid = threadIdx.x;
    int w = tid >> 6, lane = tid & 63, g = lane >> 4, li = lane & 15;
    int wr = w >> 1, wc = w & 1;
    int m0 = blockIdx.x * 128, n0 = blockIdx.y * 128;

    int srow = tid >> 3;          // 0..31
    int scol = (tid & 7) * 8;     // 0..56

    f32x4 acc[4][4];
    for (int mt = 0; mt < 4; mt++)
        for (int nt = 0; nt < 4; nt++) acc[mt][nt] = {0.f, 0.f, 0.f, 0.f};

    bf16x8 sx[4], swr[4];
    #pragma unroll
    for (int it = 0; it < 4; ++it) {
        int row = srow + 32 * it;
        sx[it]  = *reinterpret_cast<const bf16x8*>(Xb + (size_t)(m0 + row) * 1024 + scol);
        swr[it] = *reinterpret_cast<const bf16x8*>(W  + (size_t)(n0 + row) * 1024 + scol);
    }

    for (int ks = 0; ks < 16; ++ks) {
        #pragma unroll
        for (int it = 0; it < 4; ++it) {
            int row = srow + 32 * it;
            *reinterpret_cast<bf16x8*>(&XT[row][scol])  = sx[it];
            *reinterpret_cast<bf16x8*>(&WTt[row][scol]) = swr[it];
        }
        __syncthreads();
        if (ks < 15) {
            #pragma unroll
            for (int it = 0; it < 4; ++it) {
                int row = srow + 32 * it;
                sx[it]  = *reinterpret_cast<const bf16x8*>(
                    Xb + (size_t)(m0 + row) * 1024 + (ks + 1) * 64 + scol);
                swr[it] = *reinterpret_cast<const bf16x8*>(
                    W + (size_t)(n0 + row) * 1024 + (ks + 1) * 64 + scol);
            }
        }
        #pragma unroll
        for (int kk = 0; kk < 2; ++kk) {
            bf16x8 af[4], bfr[4];
            #pragma unroll
            for (int mt = 0; mt < 4; mt++)
                af[mt] = *reinterpret_cast<const bf16x8*>(&XT[64 * wr + 16 * mt + li][32 * kk + 8 * g]);
            #pragma unroll
            for (int nt = 0; nt < 4; nt++)
                bfr[nt] = *reinterpret_cast<const bf16x8*>(&WTt[64 * wc + 16 * nt + li][32 * kk + 8 * g]);
            #pragma unroll
            for (int mt = 0; mt < 4; mt++)
                #pragma unroll
                for (int nt = 0; nt < 4; nt++)
                    acc[mt][nt] = MFMA(af[mt], bfr[nt], acc[mt][nt]);
        }
        __syncthreads();
    }

    for (int mt = 0; mt < 4; mt++)
        for (int nt = 0; nt < 4; nt++) {
            int n = n0 + 64 * wc + 16 * nt + li;
            int h = n >> 6, d = n & 63;
            float bv_ = bias[n];
            for (int r = 0; r < 4; r++) {
                int m = m0 + 64 * wr + 16 * mt + 4 * g + r;
                int b = m >> 10, s = m & 1023;
                bf16 o = __float2bfloat16(acc[mt][nt][r] + bv_);
                if (proj == 0)      Qb[((size_t)(b * 16 + h) * 1024 + s) * 64 + d] = o;
                else if (proj == 1) Kb[((size_t)(b * 16 + h) * 1024 + s) * 64 + d] = o;
                else                VTb[((size_t)(b * 16 + h) * 64 + d) * 1024 + s] = o;
            }
        }
}

// ---------------------------------------------------------------------------
// Phase 2: fused attention v14 — r15 structure, mask moved off the LDS pipe:
// 4 direct f32x4 VMEM loads per kt (L2-resident, issued after barrier 1 so
// latency hides under the gather/softmax phase). Mb/sM staging removed.
// ---------------------------------------------------------------------------
__global__ __launch_bounds__(512, 4) void attn_fused(
    const bf16* __restrict__ Qg, const bf16* __restrict__ Kg,
    const bf16* __restrict__ VTg, const bf16* __restrict__ DEb,
    const float* __restrict__ mask, float* __restrict__ out) {
    const int S = 1024, D = 64;
    const float C8 = 0.18033688011112042f;   // log2(e)/8
    int p_ = blockIdx.x;
    int idx = p_ >> 3;
    int bh = (p_ & 7) * 8 + (idx >> 3);      // 8 bh per XCD
    int qb = idx & 7;
    int b = bh >> 4, h = bh & 15;
    int L0 = qb * 128;

    int tid = threadIdx.x;
    int w = tid >> 6, lane = tid & 63, g = lane >> 4, li = lane & 15;

    __shared__ __align__(16) char smem[81408];

    const char* Kh = (const char*)(Kg + (size_t)bh * S * D);
    const char* Vh = (const char*)(VTg + (size_t)bh * D * S);
    const char* DEc = (const char*)DEb;
    const float* maskb = mask + (size_t)b * S;

    int sw = (li & 7) << 4;
    int c0 = (16 * g) ^ sw;
    int c1 = (64 + 16 * g) ^ sw;
    const char* KbL = smem + li * 128;
    int gsel = (w < 4) ? (3 - w) : (7 - w);
    const char* KaL = smem + (16 * gsel + li) * 128;
    const char* Vb_ = smem + 8192 + li * 128;
    const char* Db_ = smem + 16384;

    int srow = tid >> 3;                       // 0..63
    int sc = 16 * ((lane & 7) ^ (lane >> 3));

    bf16x8 qa0, qa1;
    {
        const bf16* qrow = Qg + (size_t)bh * S * D + (size_t)(L0 + 16 * w + li) * D;
        qa0 = *reinterpret_cast<const bf16x8*>(qrow + 8 * g);
        qa1 = *reinterpret_cast<const bf16x8*>(qrow + 32 + 8 * g);
    }

    const char* qdb = smem + 40960 + 2688 * w + 170 * li - 8 * g;
    const char* kdb = smem + 62464 + 1176 * g + 32 * w + 2 * li + 30;
    char* qsp = smem + 40960 + 2688 * w + 168 * li + 8 * g;
    char* ksp = smem + 62464 + 296 * (16 * gsel + li) + ((w < 4) ? 0 : 128) + 8 * g;

    // per-kt mask pointer: lane needs mask[r0 + 16nt + 4g + r] (16B-aligned)
    const float* mq = maskb + 4 * g;

    int de00 = L0 + 1984;
    int jb = de00 % 192;
    {
        gload16(Kh + (size_t)srow * 128 + sc, smem + w * 1024);
        gload16(Vh + (size_t)srow * 2048 + sc, smem + 8192 + w * 1024);
        #pragma unroll
        for (int c = 0; c < 3; ++c) {
            int pb = jb + 64 * c; if (pb >= 192) pb -= 192;
            gload16(DEc + (size_t)(de00 + 64 * c + srow) * 128 + sc,
                    smem + 16384 + pb * 128 + w * 1024);
        }
    }

    f32x4 acc_o[4];
    for (int dt = 0; dt < 4; dt++) acc_o[dt] = {0.f, 0.f, 0.f, 0.f};
    float m_run = -1e30f, l_run = 0.f;

    __syncthreads();

    for (int kt = 0; kt < 16; ++kt) {
        int r0 = kt * 64;
        bool has_next = (kt < 15);
        int jbw = jb + 16 * w;

        if (kt) {
            gload16(Vh + (size_t)srow * 2048 + (size_t)r0 * 2 + sc, smem + 8192 + w * 1024);
        }

        __builtin_amdgcn_s_setprio(1);
        f32x4 s_acc[4];
        #pragma unroll
        for (int nt = 0; nt < 4; ++nt) {
            bf16x8 kb0 = *reinterpret_cast<const bf16x8*>(KbL + nt * 2048 + c0);
            bf16x8 kb1 = *reinterpret_cast<const bf16x8*>(KbL + nt * 2048 + c1);
            f32x4 z = {0.f, 0.f, 0.f, 0.f};
            z = MFMA(kb0, qa0, z);
            z = MFMA(kb1, qa1, z);
            s_acc[nt] = z;
        }
        {
            bf16x8 ka0 = *reinterpret_cast<const bf16x8*>(KaL + c0);
            bf16x8 ka1 = *reinterpret_cast<const bf16x8*>(KaL + c1);
            #pragma unroll
            for (int jt = 0; jt < 5; ++jt) {
                int x = jbw + 16 * jt + li;
                if (x >= 192) x -= 192;
                const char* dp = Db_ + x * 128;
                bf16x8 d0 = *reinterpret_cast<const bf16x8*>(dp + c0);
                bf16x8 d1 = *reinterpret_cast<const bf16x8*>(dp + c1);
                f32x4 aq = {0.f, 0.f, 0.f, 0.f};
                aq = MFMA(d0, qa0, aq);
                aq = MFMA(d1, qa1, aq);
                f32x4 ak = {0.f, 0.f, 0.f, 0.f};
                ak = MFMA(d0, ka0, ak);
                ak = MFMA(d1, ka1, ak);
                u32x2 uq = {pk2(aq[0], aq[1]), pk2(aq[2], aq[3])};
                *reinterpret_cast<u32x2*>(qsp + 32 * jt) = uq;
                u32x2 uk = {pk2(ak[0], ak[1]), pk2(ak[2], ak[3])};
                *reinterpret_cast<u32x2*>(ksp + 32 * jt) = uk;
            }
        }
        __builtin_amdgcn_s_setprio(0);
        __syncthreads();

        // ---- mask loads (L2-hot, latency hides under gathers/softmax) ----
        f32x4 mk4[4];
        #pragma unroll
        for (int nt = 0; nt < 4; ++nt)
            mk4[nt] = *reinterpret_cast<const f32x4*>(mq + r0 + 16 * nt);

        if (has_next) {
            int r0n = r0 + 64;
            int dlo = de00 - 64 * (kt + 1);
            int jbN = (jb >= 64) ? jb - 64 : jb + 128;
            gload16(Kh + (size_t)(r0n + srow) * 128 + sc, smem + w * 1024);
            gload16(DEc + (size_t)(dlo + srow) * 128 + sc,
                    smem + 16384 + jbN * 128 + w * 1024);
            jb = jbN;
        }

        float u[4][4];
        float lmax = -1e30f;
        #pragma unroll
        for (int nt = 0; nt < 4; ++nt) {
            #pragma unroll
            for (int r = 0; r < 4; ++r) {
                float qd = bf2f(*reinterpret_cast<const bf16*>(qdb + (126 - 32 * nt - 2 * r)));
                float kd = bf2f(*reinterpret_cast<const bf16*>(kdb + (4736 * nt + 294 * r)));
                float uu = s_acc[nt][r] + qd + kd;
                uu = __builtin_fmaf(mk4[nt][r], 8.0f, uu);
                u[nt][r] = uu;
                lmax = fmaxf(lmax, uu);
            }
        }
        float tm = quad_max(lmax);
        bool noskip = !__all(tm <= m_run);
        float scl = 1.0f;
        if (noskip) {
            float mnew = fmaxf(m_run, tm);
            scl = exp2f((m_run - mnew) * C8);
            m_run = mnew;
        }
        float nmc = -m_run * C8;
        float pv[4][4];
        #pragma unroll
        for (int nt = 0; nt < 4; ++nt)
            #pragma unroll
            for (int r = 0; r < 4; ++r)
                pv[nt][r] = exp2f(__builtin_fmaf(u[nt][r], C8, nmc));
        float t0 = (pv[0][0] + pv[0][1]) + (pv[0][2] + pv[0][3]);
        float t1 = (pv[1][0] + pv[1][1]) + (pv[1][2] + pv[1][3]);
        float t2 = (pv[2][0] + pv[2][1]) + (pv[2][2] + pv[2][3]);
        float t3 = (pv[3][0] + pv[3][1]) + (pv[3][2] + pv[3][3]);
        float qs = quad_sum((t0 + t1) + (t2 + t3));
        if (noskip) {
            l_run = l_run * scl + qs;
            #pragma unroll
            for (int dt = 0; dt < 4; dt++) acc_o[dt] *= scl;
        } else {
            l_run += qs;
        }

        // ---- P^T -> PV B-frags fully in-register (verified r13) ----
        unsigned x0 = pk2(pv[0][0], pv[0][1]), x1 = pk2(pv[0][2], pv[0][3]);
        unsigned z0 = pk2(pv[1][0], pv[1][1]), z1 = pk2(pv[1][2], pv[1][3]);
        unsigned y0 = pk2(pv[2][0], pv[2][1]), y1 = pk2(pv[2][2], pv[2][3]);
        unsigned w0 = pk2(pv[3][0], pv[3][1]), w1 = pk2(pv[3][2], pv[3][3]);
        sw32(x0, z0); sw32(x1, z1);
        sw16(x0, z0); sw16(x1, z1);
        sw32(y0, w0); sw32(y1, w1);
        sw16(y0, w0); sw16(y1, w1);
        u32x4 f0v = {x0, x1, z0, z1};
        u32x4 f1v = {y0, y1, w0, w1};
        bf16x8 pb0 = __builtin_bit_cast(bf16x8, f0v);
        bf16x8 pb1 = __builtin_bit_cast(bf16x8, f1v);

        __builtin_amdgcn_s_setprio(1);
        #pragma unroll
        for (int dt = 0; dt < 4; dt++) {
            bf16x8 va0 = *reinterpret_cast<const bf16x8*>(Vb_ + dt * 2048 + c0);
            bf16x8 va1 = *reinterpret_cast<const bf16x8*>(Vb_ + dt * 2048 + c1);
            acc_o[dt] = MFMA(va0, pb0, acc_o[dt]);
            acc_o[dt] = MFMA(va1, pb1, acc_o[dt]);
        }
        __builtin_amdgcn_s_setprio(0);

        __syncthreads();
    }

    float inv = 1.0f / l_run;
    float (*OT)[68] = reinterpret_cast<float (*)[68]>(smem);
    #pragma unroll
    for (int dt = 0; dt < 4; dt++)
        #pragma unroll
        for (int r = 0; r < 4; r++)
            OT[16 * w + li][16 * dt + 4 * g + r] = acc_o[dt][r] * inv;
    __syncthreads();
    {
        int q = tid >> 2, seg = tid & 3;
        float* gout = out + ((size_t)(b * 1024 + L0 + q)) * 1024 + h * 64 + 16 * seg;
        #pragma unroll
        for (int j = 0; j < 4; ++j)
            *reinterpret_cast<float4*>(gout + 4 * j) =
                *reinterpret_cast<const float4*>(&OT[q][16 * seg + 4 * j]);
    }
}

// ---------------------------------------------------------------------------
extern "C" void kernel_launch(void* const* d_in, const int* in_sizes, int n_in,
                              void* d_out, int out_size, void* d_ws, size_t ws_size,
                              hipStream_t stream) {
    const float* X   = (const float*)d_in[0];
    const float* msk = (const float*)d_in[1];
    const float* Wq  = (const float*)d_in[2];
    const float* bq  = (const float*)d_in[3];
    const float* Wk  = (const float*)d_in[4];
    const float* bk  = (const float*)d_in[5];
    const float* Wv  = (const float*)d_in[6];
    const float* bv  = (const float*)d_in[7];
    const float* DE  = (const float*)d_in[8];
    float* out = (float*)d_out;

    bf16* ws  = (bf16*)d_ws;
    bf16* Xb  = ws;              // 4194304
    bf16* WTb = ws + 4194304;    // 3145728
    bf16* DEb = ws + 7340032;    // 262144
    bf16* Qb  = ws + 7602176;    // 4194304
    bf16* Kb  = ws + 11796480;   // 4194304
    bf16* VTb = ws + 15990784;   // 4194304

    prep_all<<<5120, 256, 0, stream>>>(X, DE, Wq, Wk, Wv, Xb, DEb, WTb);
    proj_gemm<<<dim3(32, 8, 3), 256, 0, stream>>>(Xb, WTb, bq, bk, bv, Qb, Kb, VTb);
    attn_fused<<<512, 512, 0, stream>>>(Qb, Kb, VTb, DEb, msk, out);
}